// Round 2
// baseline (2826.130 us; speedup 1.0000x reference)
//
#include <hip/hip_runtime.h>

#define N_NODES 100000
#define D 128
#define E_EDGES 3200000
#define NPB 64                  // nodes per bucket
#define NB  1563                // ceil(N_NODES / NPB)
#define BCAP 2432               // per-bucket edge capacity: mean 2048 + 8.5 sigma
#define PBLK 512                // partition blocks
#define CHUNK (E_EDGES / PBLK)  // 6250 edges per partition block

// ---------------- kernel 1: bucket-partition edges by dst>>6 ----------------
// Packed edge word: bits [16:0] = src (<2^17), bits [22:17] = dst & 63.
__global__ __launch_bounds__(256) void partition_edges(const int* __restrict__ eidx,
                                                       int* __restrict__ gcnt,
                                                       unsigned int* __restrict__ bbuf) {
    __shared__ int hist[NB];
    __shared__ int cur[NB];
    int tid = threadIdx.x;
    for (int i = tid; i < NB; i += 256) hist[i] = 0;
    __syncthreads();

    int e0 = blockIdx.x * CHUNK;
    int e1 = e0 + CHUNK;
    for (int e = e0 + tid; e < e1; e += 256) {
        int dst = eidx[E_EDGES + e];
        atomicAdd(&hist[dst >> 6], 1);
    }
    __syncthreads();
    for (int b = tid; b < NB; b += 256)
        cur[b] = atomicAdd(&gcnt[b], hist[b]);   // reserve; cur becomes running cursor
    __syncthreads();
    for (int e = e0 + tid; e < e1; e += 256) {
        int src = eidx[e];
        int dst = eidx[E_EDGES + e];
        int b = dst >> 6;
        int slot = atomicAdd(&cur[b], 1);
        if (slot < BCAP)
            bbuf[b * BCAP + slot] = ((unsigned)(dst & 63) << 17) | (unsigned)src;
    }
}

// ---------------- kernel 2: per-bucket LDS-accumulated aggregation ----------------
// h0[n] = x[n] + sum_{edges->n} x[src]; acc initialized from x so the add is free.
__global__ __launch_bounds__(256) void aggregate(const float* __restrict__ x,
                                                 const int* __restrict__ gcnt,
                                                 const unsigned int* __restrict__ bbuf,
                                                 float* __restrict__ h0) {
    __shared__ float acc[NPB * 128];        // 32 KB
    __shared__ unsigned int elist[BCAP];    // 9.5 KB
    int b = blockIdx.x;
    int base = b * NPB;
    int nvalid = min(NPB, N_NODES - base);
    int tid = threadIdx.x;
    int cnt = min(gcnt[b], BCAP);

    for (int i = tid; i < cnt; i += 256) elist[i] = bbuf[b * BCAP + i];
    const float4* x4 = (const float4*)(x + (size_t)base * 128);
    float4* a4 = (float4*)acc;
    for (int i = tid; i < nvalid * 32; i += 256) a4[i] = x4[i];
    __syncthreads();

    int lane = tid & 63;
    int wid = tid >> 6;
    // 8 edges in flight per wave; columns (lane, lane+64) -> 2-way LDS pattern (free)
    for (int e = wid * 8; e < cnt; e += 32) {
        float v0[8], v1[8];
        int dl[8];
        int nj = min(8, cnt - e);   // wave-uniform
#pragma unroll
        for (int j = 0; j < 8; ++j) {
            if (j < nj) {
                unsigned u = elist[e + j];
                int src = (int)(u & 0x1FFFFu);
                dl[j] = (int)(u >> 17);
                v0[j] = x[src * 128 + lane];
                v1[j] = x[src * 128 + 64 + lane];
            }
        }
#pragma unroll
        for (int j = 0; j < 8; ++j) {
            if (j < nj) {
                atomicAdd(&acc[dl[j] * 128 + lane], v0[j]);
                atomicAdd(&acc[dl[j] * 128 + 64 + lane], v1[j]);
            }
        }
    }
    __syncthreads();
    float4* o4 = (float4*)(h0 + (size_t)base * 128);
    for (int i = tid; i < nvalid * 32; i += 256) o4[i] = a4[i];
}

// ---------------- kernel 3: fused 3-layer MLP (fp32, reg-tiled, LDS node tile) ------
#define HS 130

template <bool TO_LDS>
__device__ __forceinline__ void mlp_layer(float* hA,
                                          const float* __restrict__ W,
                                          const float* __restrict__ b,
                                          float* __restrict__ gout,
                                          int base, int tx, int ty) {
    float acc[8][8];
#pragma unroll
    for (int i = 0; i < 8; ++i)
#pragma unroll
        for (int j = 0; j < 8; ++j) acc[i][j] = 0.f;

    for (int k = 0; k < 128; k += 2) {
        float2 a[8];
#pragma unroll
        for (int i = 0; i < 8; ++i)
            a[i] = *(const float2*)&hA[(ty * 8 + i) * HS + k];
        float w0[8], w1[8];
#pragma unroll
        for (int j = 0; j < 8; ++j) {
            w0[j] = W[k * 128 + tx + 16 * j];
            w1[j] = W[(k + 1) * 128 + tx + 16 * j];
        }
#pragma unroll
        for (int i = 0; i < 8; ++i)
#pragma unroll
            for (int j = 0; j < 8; ++j)
                acc[i][j] += a[i].x * w0[j] + a[i].y * w1[j];
    }
    __syncthreads();
#pragma unroll
    for (int j = 0; j < 8; ++j) {
        float bv = b[tx + 16 * j];
#pragma unroll
        for (int i = 0; i < 8; ++i) {
            float v = acc[i][j] + bv;
            v = v > 0.f ? v : 0.f;
            if (TO_LDS) {
                hA[(ty * 8 + i) * HS + tx + 16 * j] = v;
            } else {
                int gn = base + ty * 8 + i;
                if (gn < N_NODES) gout[(size_t)gn * 128 + tx + 16 * j] = v;
            }
        }
    }
    __syncthreads();
}

__global__ __launch_bounds__(256, 2) void mlp(float* __restrict__ h,  // in/out = d_out
                                              const float* __restrict__ W1, const float* __restrict__ b1,
                                              const float* __restrict__ W2, const float* __restrict__ b2,
                                              const float* __restrict__ W3, const float* __restrict__ b3) {
    __shared__ float hA[128 * HS];
    int t = threadIdx.x;
    int base = blockIdx.x * 128;

    int row = t >> 1, half = t & 1;
    int gr = base + row;
    if (gr >= N_NODES) gr = N_NODES - 1;
    const float4* src = (const float4*)(h + (size_t)gr * 128 + half * 64);
    float* dl = hA + row * HS + half * 64;
#pragma unroll
    for (int q = 0; q < 16; ++q) {
        float4 v = src[q];
        dl[q * 4 + 0] = v.x;
        dl[q * 4 + 1] = v.y;
        dl[q * 4 + 2] = v.z;
        dl[q * 4 + 3] = v.w;
    }
    __syncthreads();

    int tx = t & 15;
    int ty = t >> 4;
    mlp_layer<true >(hA, W1, b1, h, base, tx, ty);
    mlp_layer<true >(hA, W2, b2, h, base, tx, ty);
    mlp_layer<false>(hA, W3, b3, h, base, tx, ty);
}

extern "C" void kernel_launch(void* const* d_in, const int* in_sizes, int n_in,
                              void* d_out, int out_size, void* d_ws, size_t ws_size,
                              hipStream_t stream) {
    const float* x  = (const float*)d_in[0];
    const float* W1 = (const float*)d_in[1];
    const float* b1 = (const float*)d_in[2];
    const float* W2 = (const float*)d_in[3];
    const float* b2 = (const float*)d_in[4];
    const float* W3 = (const float*)d_in[5];
    const float* b3 = (const float*)d_in[6];
    const int*  eidx = (const int*)d_in[7];
    float* out = (float*)d_out;

    // workspace: [gcnt: NB ints (pad to 8 KB)][bbuf: NB*BCAP u32]  ~15.2 MB
    int* gcnt = (int*)d_ws;
    unsigned int* bbuf = (unsigned int*)((char*)d_ws + 8192);

    hipMemsetAsync(gcnt, 0, 8192, stream);
    partition_edges<<<PBLK, 256, 0, stream>>>(eidx, gcnt, bbuf);
    aggregate<<<NB, 256, 0, stream>>>(x, gcnt, bbuf, out);   // h0 staged in d_out
    mlp<<<(N_NODES + 127) / 128, 256, 0, stream>>>(out, W1, b1, W2, b2, W3, b3);
}

// Round 3
// 560.607 us; speedup vs baseline: 5.0412x; 5.0412x over previous
//
#include <hip/hip_runtime.h>

#define N_NODES 100000
#define D 128
#define E_EDGES 3200000
#define BSHIFT 8
#define NPB 256                  // nodes per bin
#define NBIN 391                 // ceil(N_NODES / 256)
#define BCAP 8960                // per-bin capacity: mean 8192 + 8.5 sigma
#define PBLK 512
#define CHUNK (E_EDGES / PBLK)   // 6250

// ---------------- kernel 1: bin edges by dst>>8, packed (dstLow<<17)|src ----------
__global__ __launch_bounds__(256) void partition_edges(const int* __restrict__ eidx,
                                                       int* __restrict__ gcnt,
                                                       unsigned* __restrict__ bbuf) {
    __shared__ int hist[NBIN];
    __shared__ int cur[NBIN];
    int tid = threadIdx.x;
    for (int i = tid; i < NBIN; i += 256) hist[i] = 0;
    __syncthreads();
    int e0 = blockIdx.x * CHUNK, e1 = e0 + CHUNK;
    for (int e = e0 + tid; e < e1; e += 256)
        atomicAdd(&hist[eidx[E_EDGES + e] >> BSHIFT], 1);
    __syncthreads();
    for (int b = tid; b < NBIN; b += 256)
        cur[b] = atomicAdd(&gcnt[b], hist[b]);    // reserve dense per-(block,bin) range
    __syncthreads();
    for (int e = e0 + tid; e < e1; e += 256) {
        int src = eidx[e];
        int dst = eidx[E_EDGES + e];
        int b = dst >> BSHIFT;
        int slot = atomicAdd(&cur[b], 1);
        if (slot < BCAP)
            bbuf[(size_t)b * BCAP + slot] = ((unsigned)(dst & 255) << 17) | (unsigned)src;
    }
}

// ---------------- kernel 2: per-bin exact CSR (col + meta), LDS-local atomics -----
__global__ __launch_bounds__(256) void build_csr(const int* __restrict__ gcnt,
                                                 const unsigned* __restrict__ bbuf,
                                                 int* __restrict__ gpos,
                                                 int* __restrict__ col,
                                                 int2* __restrict__ meta) {
    __shared__ unsigned ebuf[BCAP];     // 35 KB
    __shared__ int hist[NPB], pre[NPB], cur[NPB];
    __shared__ int sh_base;
    int b = blockIdx.x, tid = threadIdx.x;
    int mb = min(gcnt[b], BCAP);
    hist[tid] = 0;
    cur[tid] = 0;
    __syncthreads();
    for (int i = tid; i < mb; i += 256) {
        unsigned w = bbuf[(size_t)b * BCAP + i];
        ebuf[i] = w;
        atomicAdd(&hist[w >> 17], 1);
    }
    __syncthreads();
    if (tid < 64) {                      // exclusive scan of 256 hist entries, wave 0
        int a0 = hist[tid * 4 + 0], a1 = hist[tid * 4 + 1];
        int a2 = hist[tid * 4 + 2], a3 = hist[tid * 4 + 3];
        int s = a0 + a1 + a2 + a3;
        int t = s;
        for (int off = 1; off < 64; off <<= 1) {
            int v = __shfl_up(t, off, 64);
            if (tid >= off) t += v;
        }
        int excl = t - s;
        pre[tid * 4 + 0] = excl;
        pre[tid * 4 + 1] = excl + a0;
        pre[tid * 4 + 2] = excl + a0 + a1;
        pre[tid * 4 + 3] = excl + a0 + a1 + a2;
    }
    if (tid == 0) sh_base = atomicAdd(gpos, mb);
    __syncthreads();
    int gbase = sh_base;
    for (int i = tid; i < mb; i += 256) {
        unsigned w = ebuf[i];
        int l = (int)(w >> 17);
        int slot = atomicAdd(&cur[l], 1);
        col[gbase + pre[l] + slot] = (int)(w & 0x1FFFFu);
    }
    __syncthreads();
    int n = (b << BSHIFT) + tid;
    if (n < N_NODES) meta[n] = make_int2(gbase + pre[tid], hist[tid]);
}

// ---------------- kernel 3: x (fp32) -> xb (bf16 RNE, packed 2/dword) -------------
__global__ __launch_bounds__(256) void to_bf16(const float* __restrict__ x,
                                               unsigned* __restrict__ xb) {
    int i = blockIdx.x * 256 + threadIdx.x;   // 6.4M output dwords
    float2 v = ((const float2*)x)[i];
    unsigned lo = __float_as_uint(v.x);
    unsigned hi = __float_as_uint(v.y);
    lo = (lo + 0x7FFFu + ((lo >> 16) & 1u)) >> 16;
    hi = (hi + 0x7FFFu + ((hi >> 16) & 1u)) >> 16;
    xb[i] = lo | (hi << 16);
}

// ---------------- kernel 4: h0 = x + sum x[src]  (wave per node, reg accumulate) --
template <bool BF16>
__global__ __launch_bounds__(256) void gather_h0(const float* __restrict__ x,
                                                 const unsigned* __restrict__ xb,
                                                 const int2* __restrict__ meta,
                                                 const int* __restrict__ col,
                                                 float* __restrict__ h0) {
    int lane = threadIdx.x & 63;
    int n = __builtin_amdgcn_readfirstlane(blockIdx.x * 4 + (threadIdx.x >> 6));
    int2 mt = meta[n];
    int base = mt.x, m = mt.y;
    const float2* xr = (const float2*)x;
    float2 acc = xr[n * 64 + lane];           // self term stays fp32
    for (int c = 0; c < m; c += 64) {
        int rem = m - c;
        int lim = rem < 64 ? rem : 64;
        int idx = 0;
        if (lane < lim) idx = col[base + c + lane];   // one coalesced index load / 64
        int j = 0;
        for (; j + 8 <= lim; j += 8) {
            if (BF16) {
                unsigned u[8];
#pragma unroll
                for (int q = 0; q < 8; ++q) {
                    int s = __shfl(idx, j + q, 64);
                    u[q] = xb[s * 64 + lane];          // 256 B/row, 1 dword/lane
                }
#pragma unroll
                for (int q = 0; q < 8; ++q) {
                    acc.x += __uint_as_float(u[q] << 16);
                    acc.y += __uint_as_float(u[q] & 0xFFFF0000u);
                }
            } else {
                float2 v[8];
#pragma unroll
                for (int q = 0; q < 8; ++q) {
                    int s = __shfl(idx, j + q, 64);
                    v[q] = xr[s * 64 + lane];
                }
#pragma unroll
                for (int q = 0; q < 8; ++q) { acc.x += v[q].x; acc.y += v[q].y; }
            }
        }
        for (; j < lim; ++j) {
            int s = __shfl(idx, j, 64);
            if (BF16) {
                unsigned u = xb[s * 64 + lane];
                acc.x += __uint_as_float(u << 16);
                acc.y += __uint_as_float(u & 0xFFFF0000u);
            } else {
                float2 v = xr[s * 64 + lane];
                acc.x += v.x; acc.y += v.y;
            }
        }
    }
    ((float2*)h0)[n * 64 + lane] = acc;
}

// ---------------- kernel 5: fused 3-layer MLP (fp32, reg-tiled, LDS node tile) ----
#define HS 130

template <bool TO_LDS>
__device__ __forceinline__ void mlp_layer(float* hA,
                                          const float* __restrict__ W,
                                          const float* __restrict__ b,
                                          float* __restrict__ gout,
                                          int base, int tx, int ty) {
    float acc[8][8];
#pragma unroll
    for (int i = 0; i < 8; ++i)
#pragma unroll
        for (int j = 0; j < 8; ++j) acc[i][j] = 0.f;

    for (int k = 0; k < 128; k += 2) {
        float2 a[8];
#pragma unroll
        for (int i = 0; i < 8; ++i)
            a[i] = *(const float2*)&hA[(ty * 8 + i) * HS + k];
        float w0[8], w1[8];
#pragma unroll
        for (int j = 0; j < 8; ++j) {
            w0[j] = W[k * 128 + tx + 16 * j];
            w1[j] = W[(k + 1) * 128 + tx + 16 * j];
        }
#pragma unroll
        for (int i = 0; i < 8; ++i)
#pragma unroll
            for (int j = 0; j < 8; ++j)
                acc[i][j] += a[i].x * w0[j] + a[i].y * w1[j];
    }
    __syncthreads();
#pragma unroll
    for (int j = 0; j < 8; ++j) {
        float bv = b[tx + 16 * j];
#pragma unroll
        for (int i = 0; i < 8; ++i) {
            float v = acc[i][j] + bv;
            v = v > 0.f ? v : 0.f;
            if (TO_LDS) {
                hA[(ty * 8 + i) * HS + tx + 16 * j] = v;
            } else {
                int gn = base + ty * 8 + i;
                if (gn < N_NODES) gout[(size_t)gn * 128 + tx + 16 * j] = v;
            }
        }
    }
    __syncthreads();
}

__global__ __launch_bounds__(256, 2) void mlp(float* __restrict__ h,
                                              const float* __restrict__ W1, const float* __restrict__ b1,
                                              const float* __restrict__ W2, const float* __restrict__ b2,
                                              const float* __restrict__ W3, const float* __restrict__ b3) {
    __shared__ float hA[128 * HS];
    int t = threadIdx.x;
    int base = blockIdx.x * 128;

    int row = t >> 1, half = t & 1;
    int gr = base + row;
    if (gr >= N_NODES) gr = N_NODES - 1;
    const float4* src = (const float4*)(h + (size_t)gr * 128 + half * 64);
    float* dl = hA + row * HS + half * 64;
#pragma unroll
    for (int q = 0; q < 16; ++q) {
        float4 v = src[q];
        dl[q * 4 + 0] = v.x;
        dl[q * 4 + 1] = v.y;
        dl[q * 4 + 2] = v.z;
        dl[q * 4 + 3] = v.w;
    }
    __syncthreads();

    int tx = t & 15;
    int ty = t >> 4;
    mlp_layer<true >(hA, W1, b1, h, base, tx, ty);
    mlp_layer<true >(hA, W2, b2, h, base, tx, ty);
    mlp_layer<false>(hA, W3, b3, h, base, tx, ty);
}

extern "C" void kernel_launch(void* const* d_in, const int* in_sizes, int n_in,
                              void* d_out, int out_size, void* d_ws, size_t ws_size,
                              hipStream_t stream) {
    const float* x  = (const float*)d_in[0];
    const float* W1 = (const float*)d_in[1];
    const float* b1 = (const float*)d_in[2];
    const float* W2 = (const float*)d_in[3];
    const float* b2 = (const float*)d_in[4];
    const float* W3 = (const float*)d_in[5];
    const float* b3 = (const float*)d_in[6];
    const int*  eidx = (const int*)d_in[7];
    float* out = (float*)d_out;

    // ws layout: [ctrl 8K: gcnt@0, gpos@4096][meta int2 x N][col E ints][bbuf | xb alias]
    const size_t OFF_META = 8192;
    const size_t OFF_COL  = OFF_META + 800256;                 // 8-aligned
    const size_t OFF_BBUF = OFF_COL + (size_t)E_EDGES * 4;     // 12.8 MB col
    const size_t SZ_BBUF  = (size_t)NBIN * BCAP * 4;           // 14.0 MB
    const size_t SZ_XB    = (size_t)N_NODES * D * 2;           // 25.6 MB (aliases bbuf)
    const size_t NEED_BF16 = OFF_BBUF + (SZ_XB > SZ_BBUF ? SZ_XB : SZ_BBUF);

    int* gcnt = (int*)d_ws;
    int* gpos = (int*)((char*)d_ws + 4096);
    int2* meta = (int2*)((char*)d_ws + OFF_META);
    int* col = (int*)((char*)d_ws + OFF_COL);
    unsigned* bbuf = (unsigned*)((char*)d_ws + OFF_BBUF);
    unsigned* xb = bbuf;   // alias: bbuf dead after build_csr, xb built after

    bool use_bf16 = ws_size >= NEED_BF16;

    hipMemsetAsync(d_ws, 0, 8192, stream);
    partition_edges<<<PBLK, 256, 0, stream>>>(eidx, gcnt, bbuf);
    build_csr<<<NBIN, 256, 0, stream>>>(gcnt, bbuf, gpos, col, meta);
    if (use_bf16) {
        to_bf16<<<(N_NODES * D / 2) / 256, 256, 0, stream>>>(x, xb);
        gather_h0<true ><<<N_NODES / 4, 256, 0, stream>>>(x, xb, meta, col, out);
    } else {
        gather_h0<false><<<N_NODES / 4, 256, 0, stream>>>(x, xb, meta, col, out);
    }
    mlp<<<(N_NODES + 127) / 128, 256, 0, stream>>>(out, W1, b1, W2, b2, W3, b3);
}

// Round 4
// 380.535 us; speedup vs baseline: 7.4267x; 1.4732x over previous
//
#include <hip/hip_runtime.h>

#define N_NODES 100000
#define D 128
#define E_EDGES 3200000
#define BSHIFT 8
#define NPB 256                  // nodes per bin
#define NBIN 391                 // ceil(N_NODES / 256)
#define BCAP 8960                // per-bin capacity: mean 8192 + 8.5 sigma
#define PBLK 512
#define CHUNK (E_EDGES / PBLK)   // 6250

typedef short bf16x8 __attribute__((ext_vector_type(8)));
typedef float f32x4 __attribute__((ext_vector_type(4)));

// ---------------- kernel 1: bin edges by dst>>8, packed (dstLow<<17)|src ----------
__global__ __launch_bounds__(256) void partition_edges(const int* __restrict__ eidx,
                                                       int* __restrict__ gcnt,
                                                       unsigned* __restrict__ bbuf) {
    __shared__ int hist[NBIN];
    __shared__ int cur[NBIN];
    int tid = threadIdx.x;
    for (int i = tid; i < NBIN; i += 256) hist[i] = 0;
    __syncthreads();
    int e0 = blockIdx.x * CHUNK, e1 = e0 + CHUNK;
    for (int e = e0 + tid; e < e1; e += 256)
        atomicAdd(&hist[eidx[E_EDGES + e] >> BSHIFT], 1);
    __syncthreads();
    for (int b = tid; b < NBIN; b += 256)
        cur[b] = atomicAdd(&gcnt[b], hist[b]);
    __syncthreads();
    for (int e = e0 + tid; e < e1; e += 256) {
        int src = eidx[e];
        int dst = eidx[E_EDGES + e];
        int b = dst >> BSHIFT;
        int slot = atomicAdd(&cur[b], 1);
        if (slot < BCAP)
            bbuf[(size_t)b * BCAP + slot] = ((unsigned)(dst & 255) << 17) | (unsigned)src;
    }
}

// ---------------- kernel 2: per-bin exact CSR (col + meta), LDS-local atomics -----
__global__ __launch_bounds__(256) void build_csr(const int* __restrict__ gcnt,
                                                 const unsigned* __restrict__ bbuf,
                                                 int* __restrict__ gpos,
                                                 int* __restrict__ col,
                                                 int2* __restrict__ meta) {
    __shared__ unsigned ebuf[BCAP];
    __shared__ int hist[NPB], pre[NPB], cur[NPB];
    __shared__ int sh_base;
    int b = blockIdx.x, tid = threadIdx.x;
    int mb = min(gcnt[b], BCAP);
    hist[tid] = 0;
    cur[tid] = 0;
    __syncthreads();
    for (int i = tid; i < mb; i += 256) {
        unsigned w = bbuf[(size_t)b * BCAP + i];
        ebuf[i] = w;
        atomicAdd(&hist[w >> 17], 1);
    }
    __syncthreads();
    if (tid < 64) {
        int a0 = hist[tid * 4 + 0], a1 = hist[tid * 4 + 1];
        int a2 = hist[tid * 4 + 2], a3 = hist[tid * 4 + 3];
        int s = a0 + a1 + a2 + a3;
        int t = s;
        for (int off = 1; off < 64; off <<= 1) {
            int v = __shfl_up(t, off, 64);
            if (tid >= off) t += v;
        }
        int excl = t - s;
        pre[tid * 4 + 0] = excl;
        pre[tid * 4 + 1] = excl + a0;
        pre[tid * 4 + 2] = excl + a0 + a1;
        pre[tid * 4 + 3] = excl + a0 + a1 + a2;
    }
    if (tid == 0) sh_base = atomicAdd(gpos, mb);
    __syncthreads();
    int gbase = sh_base;
    for (int i = tid; i < mb; i += 256) {
        unsigned w = ebuf[i];
        int l = (int)(w >> 17);
        int slot = atomicAdd(&cur[l], 1);
        col[gbase + pre[l] + slot] = (int)(w & 0x1FFFFu);
    }
    __syncthreads();
    int n = (b << BSHIFT) + tid;
    if (n < N_NODES) meta[n] = make_int2(gbase + pre[tid], hist[tid]);
}

// ---------------- kernel 3: x (fp32) -> xb (bf16 RNE, packed 2/dword) -------------
__global__ __launch_bounds__(256) void to_bf16(const float* __restrict__ x,
                                               unsigned* __restrict__ xb) {
    int i = blockIdx.x * 256 + threadIdx.x;
    float2 v = ((const float2*)x)[i];
    unsigned lo = __float_as_uint(v.x);
    unsigned hi = __float_as_uint(v.y);
    lo = (lo + 0x7FFFu + ((lo >> 16) & 1u)) >> 16;
    hi = (hi + 0x7FFFu + ((hi >> 16) & 1u)) >> 16;
    xb[i] = lo | (hi << 16);
}

// ---------------- kernel 4: h0 = x + sum x[src]  (wave per node, reg accumulate) --
template <bool BF16>
__global__ __launch_bounds__(256) void gather_h0(const float* __restrict__ x,
                                                 const unsigned* __restrict__ xb,
                                                 const int2* __restrict__ meta,
                                                 const int* __restrict__ col,
                                                 float* __restrict__ h0) {
    int lane = threadIdx.x & 63;
    int n = __builtin_amdgcn_readfirstlane(blockIdx.x * 4 + (threadIdx.x >> 6));
    int2 mt = meta[n];
    int base = mt.x, m = mt.y;
    const float2* xr = (const float2*)x;
    float2 acc = xr[n * 64 + lane];
    for (int c = 0; c < m; c += 64) {
        int rem = m - c;
        int lim = rem < 64 ? rem : 64;
        int idx = 0;
        if (lane < lim) idx = col[base + c + lane];
        int j = 0;
        for (; j + 8 <= lim; j += 8) {
            if (BF16) {
                unsigned u[8];
#pragma unroll
                for (int q = 0; q < 8; ++q) {
                    int s = __shfl(idx, j + q, 64);
                    u[q] = xb[s * 64 + lane];
                }
#pragma unroll
                for (int q = 0; q < 8; ++q) {
                    acc.x += __uint_as_float(u[q] << 16);
                    acc.y += __uint_as_float(u[q] & 0xFFFF0000u);
                }
            } else {
                float2 v[8];
#pragma unroll
                for (int q = 0; q < 8; ++q) {
                    int s = __shfl(idx, j + q, 64);
                    v[q] = xr[s * 64 + lane];
                }
#pragma unroll
                for (int q = 0; q < 8; ++q) { acc.x += v[q].x; acc.y += v[q].y; }
            }
        }
        for (; j < lim; ++j) {
            int s = __shfl(idx, j, 64);
            if (BF16) {
                unsigned u = xb[s * 64 + lane];
                acc.x += __uint_as_float(u << 16);
                acc.y += __uint_as_float(u & 0xFFFF0000u);
            } else {
                float2 v = xr[s * 64 + lane];
                acc.x += v.x; acc.y += v.y;
            }
        }
    }
    ((float2*)h0)[n * 64 + lane] = acc;
}

// ---------------- kernel 5: W (fp32 [k][n]) -> Wt (bf16 [layer][n][k]) ------------
__global__ __launch_bounds__(256) void w_prep(const float* __restrict__ W1,
                                              const float* __restrict__ W2,
                                              const float* __restrict__ W3,
                                              unsigned short* __restrict__ wt) {
    int e = blockIdx.x * 256 + threadIdx.x;    // 3 * 16384 total
    int l = e >> 14, r = e & 16383;
    int k = r >> 7, n = r & 127;
    const float* W = l == 0 ? W1 : (l == 1 ? W2 : W3);
    unsigned u = __float_as_uint(W[r]);        // coalesced read of W[k][n]
    u = (u + 0x7FFFu + ((u >> 16) & 1u)) >> 16;
    wt[l * 16384 + n * 128 + k] = (unsigned short)u;   // scattered 2B write, 192 KB total
}

// ---------------- kernel 6: fused 3-layer MLP via bf16 MFMA -----------------------
// Wave-private 32-row stripes -> no __syncthreads anywhere (LDS ops in-order/wave).
// hb stride 136 bf16: A-frag ds_read_b128 bank pattern uniform (8 words/bank floor).
#define HBW 136

__global__ __launch_bounds__(256, 4) void mlp_mfma(float* __restrict__ h,   // in=h0, out in place
                                                   const unsigned short* __restrict__ wt,
                                                   const float* __restrict__ b1,
                                                   const float* __restrict__ b2,
                                                   const float* __restrict__ b3) {
    __shared__ unsigned short hb[128 * HBW];   // 34.8 KB
    int tid = threadIdx.x;
    int w = tid >> 6, lane = tid & 63;
    int m = lane & 15, quad = lane >> 4;
    int r0 = blockIdx.x * 128 + w * 32;        // wave's first global row

    // stage: global fp32 -> LDS bf16 (coalesced 1KB/instr reads; b64 LDS writes)
    for (int it = 0; it < 16; ++it) {
        int flat = it * 64 + lane;             // float4 units within the 32x128 stripe
        int lr = flat >> 5, c4 = flat & 31;
        int gr = r0 + lr; if (gr >= N_NODES) gr = N_NODES - 1;
        float4 v = ((const float4*)h)[gr * 32 + c4];
        unsigned a0 = (__float_as_uint(v.x) + 0x8000u) >> 16;
        unsigned a1 = (__float_as_uint(v.y) + 0x8000u) & 0xFFFF0000u;
        unsigned a2 = (__float_as_uint(v.z) + 0x8000u) >> 16;
        unsigned a3 = (__float_as_uint(v.w) + 0x8000u) & 0xFFFF0000u;
        uint2 p = make_uint2(a0 | a1, a2 | a3);
        *(uint2*)&hb[(w * 32 + lr) * HBW + c4 * 4] = p;
    }

    const float* bias[3] = {b1, b2, b3};
    for (int l = 0; l < 3; ++l) {
        const unsigned short* W = wt + l * 16384;
        float bv[8];
#pragma unroll
        for (int ct = 0; ct < 8; ++ct) bv[ct] = bias[l][ct * 16 + m];

        f32x4 acc[2][8];
#pragma unroll
        for (int rt = 0; rt < 2; ++rt)
#pragma unroll
            for (int ct = 0; ct < 8; ++ct) acc[rt][ct] = (f32x4){0.f, 0.f, 0.f, 0.f};

#pragma unroll
        for (int ks = 0; ks < 4; ++ks) {
            bf16x8 a0 = *(const bf16x8*)&hb[(w * 32 + m) * HBW + ks * 32 + quad * 8];
            bf16x8 a1 = *(const bf16x8*)&hb[(w * 32 + 16 + m) * HBW + ks * 32 + quad * 8];
#pragma unroll
            for (int ct = 0; ct < 8; ++ct) {
                bf16x8 bf = *(const bf16x8*)&W[(ct * 16 + m) * 128 + ks * 32 + quad * 8];
                acc[0][ct] = __builtin_amdgcn_mfma_f32_16x16x32_bf16(a0, bf, acc[0][ct], 0, 0, 0);
                acc[1][ct] = __builtin_amdgcn_mfma_f32_16x16x32_bf16(a1, bf, acc[1][ct], 0, 0, 0);
            }
        }

        if (l < 2) {     // bias+ReLU, write back bf16 into own stripe (C/D: col=lane&15,row=quad*4+reg)
#pragma unroll
            for (int rt = 0; rt < 2; ++rt)
#pragma unroll
                for (int ct = 0; ct < 8; ++ct)
#pragma unroll
                    for (int r = 0; r < 4; ++r) {
                        float v = acc[rt][ct][r] + bv[ct];
                        v = v > 0.f ? v : 0.f;
                        unsigned u = (__float_as_uint(v) + 0x8000u) >> 16;
                        hb[(w * 32 + rt * 16 + quad * 4 + r) * HBW + ct * 16 + m] = (unsigned short)u;
                    }
        } else {         // final layer: bias+ReLU, fp32 to global
#pragma unroll
            for (int rt = 0; rt < 2; ++rt)
#pragma unroll
                for (int r = 0; r < 4; ++r) {
                    int gr = r0 + rt * 16 + quad * 4 + r;
                    if (gr < N_NODES) {
#pragma unroll
                        for (int ct = 0; ct < 8; ++ct) {
                            float v = acc[rt][ct][r] + bv[ct];
                            h[(size_t)gr * 128 + ct * 16 + m] = v > 0.f ? v : 0.f;
                        }
                    }
                }
        }
    }
}

extern "C" void kernel_launch(void* const* d_in, const int* in_sizes, int n_in,
                              void* d_out, int out_size, void* d_ws, size_t ws_size,
                              hipStream_t stream) {
    const float* x  = (const float*)d_in[0];
    const float* W1 = (const float*)d_in[1];
    const float* b1 = (const float*)d_in[2];
    const float* W2 = (const float*)d_in[3];
    const float* b2 = (const float*)d_in[4];
    const float* W3 = (const float*)d_in[5];
    const float* b3 = (const float*)d_in[6];
    const int*  eidx = (const int*)d_in[7];
    float* out = (float*)d_out;

    // ws: [gcnt@0][gpos@2048][Wt@4096 96KB][meta@102400][col][bbuf | xb alias]
    const size_t OFF_WT   = 4096;
    const size_t OFF_META = OFF_WT + 98304;                    // 102400
    const size_t OFF_COL  = OFF_META + 800256;
    const size_t OFF_BBUF = OFF_COL + (size_t)E_EDGES * 4;
    const size_t SZ_BBUF  = (size_t)NBIN * BCAP * 4;           // 14.0 MB
    const size_t SZ_XB    = (size_t)N_NODES * D * 2;           // 25.6 MB
    const size_t NEED_BF16 = OFF_BBUF + (SZ_XB > SZ_BBUF ? SZ_XB : SZ_BBUF);

    int* gcnt = (int*)d_ws;
    int* gpos = (int*)((char*)d_ws + 2048);
    unsigned short* wtb = (unsigned short*)((char*)d_ws + OFF_WT);
    int2* meta = (int2*)((char*)d_ws + OFF_META);
    int* col = (int*)((char*)d_ws + OFF_COL);
    unsigned* bbuf = (unsigned*)((char*)d_ws + OFF_BBUF);
    unsigned* xb = bbuf;   // bbuf dead after build_csr

    bool use_bf16 = ws_size >= NEED_BF16;

    hipMemsetAsync(d_ws, 0, 4096, stream);
    w_prep<<<192, 256, 0, stream>>>(W1, W2, W3, wtb);
    partition_edges<<<PBLK, 256, 0, stream>>>(eidx, gcnt, bbuf);
    build_csr<<<NBIN, 256, 0, stream>>>(gcnt, bbuf, gpos, col, meta);
    if (use_bf16) {
        to_bf16<<<(N_NODES * D / 2) / 256, 256, 0, stream>>>(x, xb);
        gather_h0<true ><<<N_NODES / 4, 256, 0, stream>>>(x, xb, meta, col, out);
    } else {
        gather_h0<false><<<N_NODES / 4, 256, 0, stream>>>(x, xb, meta, col, out);
    }
    mlp_mfma<<<(N_NODES + 127) / 128, 256, 0, stream>>>(out, wtb, b1, b2, b3);
}

// Round 5
// 349.156 us; speedup vs baseline: 8.0942x; 1.0899x over previous
//
#include <hip/hip_runtime.h>

#define N_NODES 100000
#define D 128
#define E_EDGES 3200000
#define BSHIFT 8
#define NPB 256                  // nodes per bin
#define NBIN 391                 // ceil(N_NODES / 256)
#define BCAP 8960                // per-bin capacity: mean 8192 + 8.5 sigma
#define PBLK 512
#define CHUNK (E_EDGES / PBLK)   // 6250

typedef short bf16x8 __attribute__((ext_vector_type(8)));
typedef float f32x4 __attribute__((ext_vector_type(4)));

__device__ __forceinline__ unsigned rne_bf16(float f) {   // fp32 -> bf16 (RNE), low 16
    unsigned u = __float_as_uint(f);
    return (u + 0x7FFFu + ((u >> 16) & 1u)) >> 16;
}

// ---------------- kernel 1: Wt (bf16 [layer][n][k]) + zero control block ----------
__global__ __launch_bounds__(256) void w_prep(const float* __restrict__ W1,
                                              const float* __restrict__ W2,
                                              const float* __restrict__ W3,
                                              unsigned short* __restrict__ wt,
                                              int* __restrict__ ctrl) {
    int e = blockIdx.x * 256 + threadIdx.x;    // 192 blocks: 49152 threads
    if (e < 1024) ctrl[e] = 0;                 // gcnt@0, gpos@dword512
    if (e < 3 * 16384) {
        int l = e >> 14, r = e & 16383;
        int k = r >> 7, n = r & 127;
        const float* W = l == 0 ? W1 : (l == 1 ? W2 : W3);
        wt[l * 16384 + n * 128 + k] = (unsigned short)rne_bf16(W[r]);
    }
}

// ---------------- kernel 2: x (fp32) -> xb (bf16 packed 2/dword), in d_out --------
__global__ __launch_bounds__(256) void to_bf16(const float* __restrict__ x,
                                               unsigned* __restrict__ xb) {
    int i = blockIdx.x * 256 + threadIdx.x;    // 6.4M dwords
    float2 v = ((const float2*)x)[i];
    xb[i] = rne_bf16(v.x) | (rne_bf16(v.y) << 16);
}

// ---------------- kernel 3: bin edges by dst>>8 (eidx read ONCE, LDS-staged) ------
__global__ __launch_bounds__(256) void partition_edges(const int* __restrict__ eidx,
                                                       int* __restrict__ gcnt,
                                                       unsigned* __restrict__ bbuf) {
    __shared__ int ssrc[CHUNK];    // 25 KB
    __shared__ int sdst[CHUNK];    // 25 KB
    __shared__ int hist[NBIN];
    __shared__ int cur[NBIN];
    int tid = threadIdx.x;
    for (int i = tid; i < NBIN; i += 256) hist[i] = 0;
    __syncthreads();
    int e0 = blockIdx.x * CHUNK;
    for (int i = tid; i < CHUNK; i += 256) {
        int s = eidx[e0 + i];
        int d = eidx[E_EDGES + e0 + i];
        ssrc[i] = s;
        sdst[i] = d;
        atomicAdd(&hist[d >> BSHIFT], 1);
    }
    __syncthreads();
    for (int b = tid; b < NBIN; b += 256)
        cur[b] = atomicAdd(&gcnt[b], hist[b]);    // reserve dense per-(block,bin) range
    __syncthreads();
    for (int i = tid; i < CHUNK; i += 256) {
        int d = sdst[i];
        int b = d >> BSHIFT;
        int slot = atomicAdd(&cur[b], 1);
        if (slot < BCAP)
            bbuf[(size_t)b * BCAP + slot] = ((unsigned)(d & 255) << 17) | (unsigned)ssrc[i];
    }
}

// ---------------- kernel 4: per-bin exact CSR (col + meta), LDS-local atomics -----
__global__ __launch_bounds__(256) void build_csr(const int* __restrict__ gcnt,
                                                 const unsigned* __restrict__ bbuf,
                                                 int* __restrict__ gpos,
                                                 int* __restrict__ col,
                                                 int2* __restrict__ meta) {
    __shared__ unsigned ebuf[BCAP];
    __shared__ int hist[NPB], pre[NPB], cur[NPB];
    __shared__ int sh_base;
    int b = blockIdx.x, tid = threadIdx.x;
    int mb = min(gcnt[b], BCAP);
    hist[tid] = 0;
    cur[tid] = 0;
    __syncthreads();
    for (int i = tid; i < mb; i += 256) {
        unsigned w = bbuf[(size_t)b * BCAP + i];
        ebuf[i] = w;
        atomicAdd(&hist[w >> 17], 1);
    }
    __syncthreads();
    if (tid < 64) {
        int a0 = hist[tid * 4 + 0], a1 = hist[tid * 4 + 1];
        int a2 = hist[tid * 4 + 2], a3 = hist[tid * 4 + 3];
        int s = a0 + a1 + a2 + a3;
        int t = s;
        for (int off = 1; off < 64; off <<= 1) {
            int v = __shfl_up(t, off, 64);
            if (tid >= off) t += v;
        }
        int excl = t - s;
        pre[tid * 4 + 0] = excl;
        pre[tid * 4 + 1] = excl + a0;
        pre[tid * 4 + 2] = excl + a0 + a1;
        pre[tid * 4 + 3] = excl + a0 + a1 + a2;
    }
    if (tid == 0) sh_base = atomicAdd(gpos, mb);
    __syncthreads();
    int gbase = sh_base;
    for (int i = tid; i < mb; i += 256) {
        unsigned w = ebuf[i];
        int l = (int)(w >> 17);
        int slot = atomicAdd(&cur[l], 1);
        col[gbase + pre[l] + slot] = (int)(w & 0x1FFFFu);
    }
    __syncthreads();
    int n = (b << BSHIFT) + tid;
    if (n < N_NODES) meta[n] = make_int2(gbase + pre[tid], hist[tid]);
}

// ---------------- kernel 5: h0b(bf16) = bf16(x + sum x[src])  (wave per node) -----
__global__ __launch_bounds__(256) void gather_h0(const float* __restrict__ x,
                                                 const unsigned* __restrict__ xb,
                                                 const int2* __restrict__ meta,
                                                 const int* __restrict__ col,
                                                 unsigned* __restrict__ h0b) {
    int lane = threadIdx.x & 63;
    int n = __builtin_amdgcn_readfirstlane(blockIdx.x * 4 + (threadIdx.x >> 6));
    int2 mt = meta[n];
    int base = mt.x, m = mt.y;
    float2 acc = ((const float2*)x)[n * 64 + lane];   // self term fp32
    for (int c = 0; c < m; c += 64) {
        int rem = m - c;
        int lim = rem < 64 ? rem : 64;
        int idx = 0;
        if (lane < lim) idx = col[base + c + lane];   // one coalesced index load / 64
        int j = 0;
        for (; j + 16 <= lim; j += 16) {              // 16 rows in flight
            unsigned u[16];
#pragma unroll
            for (int q = 0; q < 16; ++q) {
                int s = __shfl(idx, j + q, 64);
                u[q] = xb[s * 64 + lane];
            }
#pragma unroll
            for (int q = 0; q < 16; ++q) {
                acc.x += __uint_as_float(u[q] << 16);
                acc.y += __uint_as_float(u[q] & 0xFFFF0000u);
            }
        }
        for (; j + 4 <= lim; j += 4) {
            unsigned u[4];
#pragma unroll
            for (int q = 0; q < 4; ++q) {
                int s = __shfl(idx, j + q, 64);
                u[q] = xb[s * 64 + lane];
            }
#pragma unroll
            for (int q = 0; q < 4; ++q) {
                acc.x += __uint_as_float(u[q] << 16);
                acc.y += __uint_as_float(u[q] & 0xFFFF0000u);
            }
        }
        for (; j < lim; ++j) {
            int s = __shfl(idx, j, 64);
            unsigned u = xb[s * 64 + lane];
            acc.x += __uint_as_float(u << 16);
            acc.y += __uint_as_float(u & 0xFFFF0000u);
        }
    }
    h0b[n * 64 + lane] = rne_bf16(acc.x) | (rne_bf16(acc.y) << 16);   // ONE rounding (same as before)
}

// ---------------- kernel 6: fused 3-layer MLP via bf16 MFMA (reads bf16 h0b) ------
#define HBW 136

__global__ __launch_bounds__(256, 4) void mlp_mfma(const unsigned* __restrict__ h0b,
                                                   float* __restrict__ out,
                                                   const unsigned short* __restrict__ wt,
                                                   const float* __restrict__ b1,
                                                   const float* __restrict__ b2,
                                                   const float* __restrict__ b3) {
    __shared__ unsigned short hb[128 * HBW];   // 34.8 KB
    int tid = threadIdx.x;
    int w = tid >> 6, lane = tid & 63;
    int m = lane & 15, quad = lane >> 4;
    int r0 = blockIdx.x * 128 + w * 32;        // wave's 32-row stripe (wave-private: no barriers)

    // stage: global bf16 -> LDS (pure copy, uint4 = 8 cols)
    for (int it = 0; it < 8; ++it) {
        int flat = it * 64 + lane;             // uint4 units: 512 per stripe
        int lr = flat >> 4, c4 = flat & 15;
        int gr = r0 + lr; if (gr >= N_NODES) gr = N_NODES - 1;
        uint4 v = ((const uint4*)h0b)[gr * 16 + c4];
        *(uint4*)&hb[(w * 32 + lr) * HBW + c4 * 8] = v;
    }

    const float* bias[3] = {b1, b2, b3};
    for (int l = 0; l < 3; ++l) {
        const unsigned short* W = wt + l * 16384;
        float bv[8];
#pragma unroll
        for (int ct = 0; ct < 8; ++ct) bv[ct] = bias[l][ct * 16 + m];

        f32x4 acc[2][8];
#pragma unroll
        for (int rt = 0; rt < 2; ++rt)
#pragma unroll
            for (int ct = 0; ct < 8; ++ct) acc[rt][ct] = (f32x4){0.f, 0.f, 0.f, 0.f};

#pragma unroll
        for (int ks = 0; ks < 4; ++ks) {
            bf16x8 a0 = *(const bf16x8*)&hb[(w * 32 + m) * HBW + ks * 32 + quad * 8];
            bf16x8 a1 = *(const bf16x8*)&hb[(w * 32 + 16 + m) * HBW + ks * 32 + quad * 8];
#pragma unroll
            for (int ct = 0; ct < 8; ++ct) {
                bf16x8 bf = *(const bf16x8*)&W[(ct * 16 + m) * 128 + ks * 32 + quad * 8];
                acc[0][ct] = __builtin_amdgcn_mfma_f32_16x16x32_bf16(a0, bf, acc[0][ct], 0, 0, 0);
                acc[1][ct] = __builtin_amdgcn_mfma_f32_16x16x32_bf16(a1, bf, acc[1][ct], 0, 0, 0);
            }
        }

        if (l < 2) {     // bias+ReLU -> bf16 back into own stripe (C/D: col=lane&15, row=quad*4+reg)
#pragma unroll
            for (int rt = 0; rt < 2; ++rt)
#pragma unroll
                for (int ct = 0; ct < 8; ++ct)
#pragma unroll
                    for (int r = 0; r < 4; ++r) {
                        float v = acc[rt][ct][r] + bv[ct];
                        v = v > 0.f ? v : 0.f;
                        hb[(w * 32 + rt * 16 + quad * 4 + r) * HBW + ct * 16 + m] =
                            (unsigned short)rne_bf16(v);
                    }
        } else {         // final layer: bias+ReLU, fp32 to global
#pragma unroll
            for (int rt = 0; rt < 2; ++rt)
#pragma unroll
                for (int r = 0; r < 4; ++r) {
                    int gr = r0 + rt * 16 + quad * 4 + r;
                    if (gr < N_NODES) {
#pragma unroll
                        for (int ct = 0; ct < 8; ++ct) {
                            float v = acc[rt][ct][r] + bv[ct];
                            out[(size_t)gr * 128 + ct * 16 + m] = v > 0.f ? v : 0.f;
                        }
                    }
                }
        }
    }
}

extern "C" void kernel_launch(void* const* d_in, const int* in_sizes, int n_in,
                              void* d_out, int out_size, void* d_ws, size_t ws_size,
                              hipStream_t stream) {
    const float* x  = (const float*)d_in[0];
    const float* W1 = (const float*)d_in[1];
    const float* b1 = (const float*)d_in[2];
    const float* W2 = (const float*)d_in[3];
    const float* b2 = (const float*)d_in[4];
    const float* W3 = (const float*)d_in[5];
    const float* b3 = (const float*)d_in[6];
    const int*  eidx = (const int*)d_in[7];
    float* out = (float*)d_out;

    // ws: [ctrl 4K: gcnt@0,gpos@2048][Wt 96K][meta][col][bbuf | h0b alias]  need 39.3 MB
    const size_t OFF_WT   = 4096;
    const size_t OFF_META = OFF_WT + 98304;
    const size_t OFF_COL  = OFF_META + 800256;
    const size_t OFF_BBUF = OFF_COL + (size_t)E_EDGES * 4;

    int* ctrl = (int*)d_ws;
    int* gcnt = (int*)d_ws;
    int* gpos = (int*)((char*)d_ws + 2048);
    unsigned short* wtb = (unsigned short*)((char*)d_ws + OFF_WT);
    int2* meta = (int2*)((char*)d_ws + OFF_META);
    int* col = (int*)((char*)d_ws + OFF_COL);
    unsigned* bbuf = (unsigned*)((char*)d_ws + OFF_BBUF);
    unsigned* h0b = bbuf;                       // alias: bbuf dead after build_csr
    unsigned* xb = (unsigned*)d_out;            // xb lives in d_out until mlp's final write

    w_prep<<<192, 256, 0, stream>>>(W1, W2, W3, wtb, ctrl);
    to_bf16<<<(N_NODES * D / 2) / 256, 256, 0, stream>>>(x, xb);
    partition_edges<<<PBLK, 256, 0, stream>>>(eidx, gcnt, bbuf);
    build_csr<<<NBIN, 256, 0, stream>>>(gcnt, bbuf, gpos, col, meta);
    gather_h0<<<N_NODES / 4, 256, 0, stream>>>(x, xb, meta, col, h0b);
    mlp_mfma<<<(N_NODES + 127) / 128, 256, 0, stream>>>(h0b, out, wtb, b1, b2, b3);
}

// Round 7
// 337.239 us; speedup vs baseline: 8.3802x; 1.0353x over previous
//
#include <hip/hip_runtime.h>

#define N_NODES 100000
#define D 128
#define E_EDGES 3200000
#define BSHIFT 8
#define NPB 256                  // nodes per bin
#define NBIN 391                 // ceil(N_NODES / 256)
#define BCAP 8960                // per-bin capacity: mean 8192 + 8.5 sigma
#define PBLK 625
#define CHUNK 5120               // edges per partition block (int4-friendly)

typedef short bf16x8 __attribute__((ext_vector_type(8)));
typedef float f32x4 __attribute__((ext_vector_type(4)));

__device__ __forceinline__ unsigned rne_bf16(float f) {   // fp32 -> bf16 (RNE), low 16
    unsigned u = __float_as_uint(f);
    return (u + 0x7FFFu + ((u >> 16) & 1u)) >> 16;
}
__device__ __forceinline__ float bf_lo(unsigned u) { return __uint_as_float(u << 16); }
__device__ __forceinline__ float bf_hi(unsigned u) { return __uint_as_float(u & 0xFFFF0000u); }

// ---------------- kernel 1: xb = bf16(x), + Wt prep + ctrl zero (fused) -----------
__global__ __launch_bounds__(256) void prep(const float* __restrict__ x,
                                            const float* __restrict__ W1,
                                            const float* __restrict__ W2,
                                            const float* __restrict__ W3,
                                            unsigned* __restrict__ xb,
                                            unsigned short* __restrict__ wt,
                                            int* __restrict__ ctrl) {
    int i = blockIdx.x * 256 + threadIdx.x;    // 25000 blocks: 6.4M dwords
    float2 v = ((const float2*)x)[i];
    xb[i] = rne_bf16(v.x) | (rne_bf16(v.y) << 16);
    if (i < 1024) ctrl[i] = 0;                 // gcnt@0, gpos@dword512
    if (i < 3 * 16384) {
        int l = i >> 14, r = i & 16383;
        int k = r >> 7, n = r & 127;
        const float* W = l == 0 ? W1 : (l == 1 ? W2 : W3);
        wt[l * 16384 + n * 128 + k] = (unsigned short)rne_bf16(W[r]);
    }
}

// ---------------- kernel 2: bin edges by dst>>8 (int4 loads, LDS-staged) ----------
__global__ __launch_bounds__(256) void partition_edges(const int* __restrict__ eidx,
                                                       int* __restrict__ gcnt,
                                                       unsigned* __restrict__ bbuf) {
    __shared__ int ssrc[CHUNK];    // 20 KB
    __shared__ int sdst[CHUNK];    // 20 KB
    __shared__ int hist[NBIN];
    __shared__ int cur[NBIN];
    int tid = threadIdx.x;
    for (int i = tid; i < NBIN; i += 256) hist[i] = 0;
    __syncthreads();
    int e0 = blockIdx.x * CHUNK;
    const int4* s4 = (const int4*)(eidx + e0);
    const int4* d4 = (const int4*)(eidx + E_EDGES + e0);
#pragma unroll
    for (int it = 0; it < 5; ++it) {
        int i = it * 256 + tid;
        int4 s = s4[i], d = d4[i];
        ((int4*)ssrc)[i] = s;
        ((int4*)sdst)[i] = d;
        atomicAdd(&hist[d.x >> BSHIFT], 1);
        atomicAdd(&hist[d.y >> BSHIFT], 1);
        atomicAdd(&hist[d.z >> BSHIFT], 1);
        atomicAdd(&hist[d.w >> BSHIFT], 1);
    }
    __syncthreads();
    for (int b = tid; b < NBIN; b += 256)
        cur[b] = atomicAdd(&gcnt[b], hist[b]);    // reserve dense per-(block,bin) range
    __syncthreads();
#pragma unroll
    for (int it = 0; it < 5; ++it) {
        int i = it * 256 + tid;
        int4 s = ((const int4*)ssrc)[i];
        int4 d = ((const int4*)sdst)[i];
        int sv[4] = {s.x, s.y, s.z, s.w};
        int dv[4] = {d.x, d.y, d.z, d.w};
#pragma unroll
        for (int q = 0; q < 4; ++q) {
            int b = dv[q] >> BSHIFT;
            int slot = atomicAdd(&cur[b], 1);
            if (slot < BCAP)
                bbuf[(size_t)b * BCAP + slot] =
                    ((unsigned)(dv[q] & 255) << 17) | (unsigned)sv[q];
        }
    }
}

// ---------------- kernel 3: per-bin exact CSR (col + meta), LDS-local atomics -----
__global__ __launch_bounds__(256) void build_csr(const int* __restrict__ gcnt,
                                                 const unsigned* __restrict__ bbuf,
                                                 int* __restrict__ gpos,
                                                 int* __restrict__ col,
                                                 int2* __restrict__ meta) {
    __shared__ unsigned ebuf[BCAP];
    __shared__ int hist[NPB], pre[NPB], cur[NPB];
    __shared__ int sh_base;
    int b = blockIdx.x, tid = threadIdx.x;
    int mb = min(gcnt[b], BCAP);
    hist[tid] = 0;
    cur[tid] = 0;
    __syncthreads();
    for (int i = tid; i < mb; i += 256) {
        unsigned w = bbuf[(size_t)b * BCAP + i];
        ebuf[i] = w;
        atomicAdd(&hist[w >> 17], 1);
    }
    __syncthreads();
    if (tid < 64) {
        int a0 = hist[tid * 4 + 0], a1 = hist[tid * 4 + 1];
        int a2 = hist[tid * 4 + 2], a3 = hist[tid * 4 + 3];
        int s = a0 + a1 + a2 + a3;
        int t = s;
        for (int off = 1; off < 64; off <<= 1) {
            int v = __shfl_up(t, off, 64);
            if (tid >= off) t += v;
        }
        int excl = t - s;
        pre[tid * 4 + 0] = excl;
        pre[tid * 4 + 1] = excl + a0;
        pre[tid * 4 + 2] = excl + a0 + a1;
        pre[tid * 4 + 3] = excl + a0 + a1 + a2;
    }
    if (tid == 0) sh_base = atomicAdd(gpos, mb);
    __syncthreads();
    int gbase = sh_base;
    for (int i = tid; i < mb; i += 256) {
        unsigned w = ebuf[i];
        int l = (int)(w >> 17);
        int slot = atomicAdd(&cur[l], 1);
        col[gbase + pre[l] + slot] = (int)(w & 0x1FFFFu);
    }
    __syncthreads();
    int n = (b << BSHIFT) + tid;
    if (n < N_NODES) meta[n] = make_int2(gbase + pre[tid], hist[tid]);
}

// ---------------- kernel 4: h0b = bf16(x + sum x[src]), 4 rows per load instr -----
// Wave layout: 16 lanes x uint4 = one 256B row; groups g=0..3 cover 4 rows/instr.
// Self term ONLY in group 0 (round-6 bug: all groups had it -> counted 4x).
// Cross-group partials folded by shfl_xor(16/32) butterfly at the end.
__global__ __launch_bounds__(256) void gather_h0(const unsigned* __restrict__ xb,
                                                 const int2* __restrict__ meta,
                                                 const int* __restrict__ col,
                                                 unsigned* __restrict__ h0b) {
    int lane = threadIdx.x & 63;
    int n = __builtin_amdgcn_readfirstlane(blockIdx.x * 4 + (threadIdx.x >> 6));
    int g = lane >> 4;         // row group within a 4-row load batch
    int li = lane & 15;        // uint4 index within the row (8 bf16 cols)
    int2 mt = meta[n];
    int base = mt.x, m = mt.y;

    const uint4* xb4 = (const uint4*)xb;
    float acc[8];
    if (g == 0) {              // self term exactly once across the fold
        uint4 sv = xb4[n * 16 + li];
        acc[0] = bf_lo(sv.x); acc[1] = bf_hi(sv.x);
        acc[2] = bf_lo(sv.y); acc[3] = bf_hi(sv.y);
        acc[4] = bf_lo(sv.z); acc[5] = bf_hi(sv.z);
        acc[6] = bf_lo(sv.w); acc[7] = bf_hi(sv.w);
    } else {
#pragma unroll
        for (int k = 0; k < 8; ++k) acc[k] = 0.f;
    }

    for (int c = 0; c < m; c += 64) {
        int rem = m - c;
        int lim = rem < 64 ? rem : 64;
        int idx = 0;
        if (lane < lim) idx = col[base + c + lane];   // one coalesced index load / 64
        int j = 0;
        for (; j + 16 <= lim; j += 16) {              // 16 rows via 4 dwordx4 loads
            uint4 u[4];
#pragma unroll
            for (int t = 0; t < 4; ++t) {
                int s = __shfl(idx, j + t * 4 + g, 64);
                u[t] = xb4[s * 16 + li];
            }
#pragma unroll
            for (int t = 0; t < 4; ++t) {
                acc[0] += bf_lo(u[t].x); acc[1] += bf_hi(u[t].x);
                acc[2] += bf_lo(u[t].y); acc[3] += bf_hi(u[t].y);
                acc[4] += bf_lo(u[t].z); acc[5] += bf_hi(u[t].z);
                acc[6] += bf_lo(u[t].w); acc[7] += bf_hi(u[t].w);
            }
        }
        for (; j + 4 <= lim; j += 4) {                // 4 rows via 1 load
            int s = __shfl(idx, j + g, 64);
            uint4 u = xb4[s * 16 + li];
            acc[0] += bf_lo(u.x); acc[1] += bf_hi(u.x);
            acc[2] += bf_lo(u.y); acc[3] += bf_hi(u.y);
            acc[4] += bf_lo(u.z); acc[5] += bf_hi(u.z);
            acc[6] += bf_lo(u.w); acc[7] += bf_hi(u.w);
        }
        int tail = lim - j;                           // 0..3 rows
        if (tail > 0) {
            int s = __shfl(idx, j + (g < tail ? g : 0), 64);
            if (g < tail) {
                uint4 u = xb4[s * 16 + li];
                acc[0] += bf_lo(u.x); acc[1] += bf_hi(u.x);
                acc[2] += bf_lo(u.y); acc[3] += bf_hi(u.y);
                acc[4] += bf_lo(u.z); acc[5] += bf_hi(u.z);
                acc[6] += bf_lo(u.w); acc[7] += bf_hi(u.w);
            }
        }
    }
#pragma unroll
    for (int k = 0; k < 8; ++k) {                     // fold 4 row-groups
        acc[k] += __shfl_xor(acc[k], 16, 64);
        acc[k] += __shfl_xor(acc[k], 32, 64);
    }
    if (g == 0) {
        uint4 o;
        o.x = rne_bf16(acc[0]) | (rne_bf16(acc[1]) << 16);
        o.y = rne_bf16(acc[2]) | (rne_bf16(acc[3]) << 16);
        o.z = rne_bf16(acc[4]) | (rne_bf16(acc[5]) << 16);
        o.w = rne_bf16(acc[6]) | (rne_bf16(acc[7]) << 16);
        ((uint4*)h0b)[n * 16 + li] = o;
    }
}

// ---------------- kernel 5: fused 3-layer MLP via bf16 MFMA (reads bf16 h0b) ------
#define HBW 136

__global__ __launch_bounds__(256, 4) void mlp_mfma(const unsigned* __restrict__ h0b,
                                                   float* __restrict__ out,
                                                   const unsigned short* __restrict__ wt,
                                                   const float* __restrict__ b1,
                                                   const float* __restrict__ b2,
                                                   const float* __restrict__ b3) {
    __shared__ unsigned short hb[128 * HBW];   // 34.8 KB
    int tid = threadIdx.x;
    int w = tid >> 6, lane = tid & 63;
    int m = lane & 15, quad = lane >> 4;
    int r0 = blockIdx.x * 128 + w * 32;        // wave-private 32-row stripe: no barriers

    for (int it = 0; it < 8; ++it) {
        int flat = it * 64 + lane;
        int lr = flat >> 4, c4 = flat & 15;
        int gr = r0 + lr; if (gr >= N_NODES) gr = N_NODES - 1;
        uint4 v = ((const uint4*)h0b)[gr * 16 + c4];
        *(uint4*)&hb[(w * 32 + lr) * HBW + c4 * 8] = v;
    }

    const float* bias[3] = {b1, b2, b3};
    for (int l = 0; l < 3; ++l) {
        const unsigned short* W = wt + l * 16384;
        float bv[8];
#pragma unroll
        for (int ct = 0; ct < 8; ++ct) bv[ct] = bias[l][ct * 16 + m];

        f32x4 acc[2][8];
#pragma unroll
        for (int rt = 0; rt < 2; ++rt)
#pragma unroll
            for (int ct = 0; ct < 8; ++ct) acc[rt][ct] = (f32x4){0.f, 0.f, 0.f, 0.f};

#pragma unroll
        for (int ks = 0; ks < 4; ++ks) {
            bf16x8 a0 = *(const bf16x8*)&hb[(w * 32 + m) * HBW + ks * 32 + quad * 8];
            bf16x8 a1 = *(const bf16x8*)&hb[(w * 32 + 16 + m) * HBW + ks * 32 + quad * 8];
#pragma unroll
            for (int ct = 0; ct < 8; ++ct) {
                bf16x8 bf = *(const bf16x8*)&W[(ct * 16 + m) * 128 + ks * 32 + quad * 8];
                acc[0][ct] = __builtin_amdgcn_mfma_f32_16x16x32_bf16(a0, bf, acc[0][ct], 0, 0, 0);
                acc[1][ct] = __builtin_amdgcn_mfma_f32_16x16x32_bf16(a1, bf, acc[1][ct], 0, 0, 0);
            }
        }

        if (l < 2) {
#pragma unroll
            for (int rt = 0; rt < 2; ++rt)
#pragma unroll
                for (int ct = 0; ct < 8; ++ct)
#pragma unroll
                    for (int r = 0; r < 4; ++r) {
                        float v = acc[rt][ct][r] + bv[ct];
                        v = v > 0.f ? v : 0.f;
                        hb[(w * 32 + rt * 16 + quad * 4 + r) * HBW + ct * 16 + m] =
                            (unsigned short)rne_bf16(v);
                    }
        } else {
#pragma unroll
            for (int rt = 0; rt < 2; ++rt)
#pragma unroll
                for (int r = 0; r < 4; ++r) {
                    int gr = r0 + rt * 16 + quad * 4 + r;
                    if (gr < N_NODES) {
#pragma unroll
                        for (int ct = 0; ct < 8; ++ct) {
                            float v = acc[rt][ct][r] + bv[ct];
                            out[(size_t)gr * 128 + ct * 16 + m] = v > 0.f ? v : 0.f;
                        }
                    }
                }
        }
    }
}

extern "C" void kernel_launch(void* const* d_in, const int* in_sizes, int n_in,
                              void* d_out, int out_size, void* d_ws, size_t ws_size,
                              hipStream_t stream) {
    const float* x  = (const float*)d_in[0];
    const float* W1 = (const float*)d_in[1];
    const float* b1 = (const float*)d_in[2];
    const float* W2 = (const float*)d_in[3];
    const float* b2 = (const float*)d_in[4];
    const float* W3 = (const float*)d_in[5];
    const float* b3 = (const float*)d_in[6];
    const int*  eidx = (const int*)d_in[7];
    float* out = (float*)d_out;

    // ws: [ctrl 4K: gcnt@0,gpos@2048][Wt 96K][meta][col][bbuf | h0b alias]  need 39.3 MB
    const size_t OFF_WT   = 4096;
    const size_t OFF_META = OFF_WT + 98304;
    const size_t OFF_COL  = OFF_META + 800256;
    const size_t OFF_BBUF = OFF_COL + (size_t)E_EDGES * 4;

    int* ctrl = (int*)d_ws;
    int* gcnt = (int*)d_ws;
    int* gpos = (int*)((char*)d_ws + 2048);
    unsigned short* wtb = (unsigned short*)((char*)d_ws + OFF_WT);
    int2* meta = (int2*)((char*)d_ws + OFF_META);
    int* col = (int*)((char*)d_ws + OFF_COL);
    unsigned* bbuf = (unsigned*)((char*)d_ws + OFF_BBUF);
    unsigned* h0b = bbuf;                       // alias: bbuf dead after build_csr
    unsigned* xb = (unsigned*)d_out;            // xb lives in d_out until mlp's final write

    prep<<<25000, 256, 0, stream>>>(x, W1, W2, W3, xb, wtb, ctrl);
    partition_edges<<<PBLK, 256, 0, stream>>>(eidx, gcnt, bbuf);
    build_csr<<<NBIN, 256, 0, stream>>>(gcnt, bbuf, gpos, col, meta);
    gather_h0<<<N_NODES / 4, 256, 0, stream>>>(xb, meta, col, h0b);
    mlp_mfma<<<(N_NODES + 127) / 128, 256, 0, stream>>>(h0b, out, wtb, b1, b2, b3);
}